// Round 6
// baseline (447.321 us; speedup 1.0000x reference)
//
#include <hip/hip_runtime.h>
#include <stdint.h>
#include <stddef.h>

#define BB 2
#define LL 2048
#define DD 1024
#define HH 16
#define DHH 64
#define NH 1024  // H*DH

typedef __attribute__((ext_vector_type(8))) __bf16 bf16x8;
typedef __attribute__((ext_vector_type(4))) float f32x4;

__device__ __forceinline__ f32x4 mfma_bf16(bf16x8 a, bf16x8 b, f32x4 c) {
    return __builtin_amdgcn_mfma_f32_16x16x32_bf16(a, b, c, 0, 0, 0);
}

__device__ __forceinline__ unsigned short f2bf(float f) {
    union { float f; unsigned u; } v; v.f = f;
    unsigned r = v.u + 0x7FFFu + ((v.u >> 16) & 1u);  // RNE
    return (unsigned short)(r >> 16);
}

__device__ __forceinline__ float bf2f(unsigned short s) {
    union { unsigned u; float f; } v; v.u = ((unsigned)s) << 16;
    return v.f;
}

__device__ __forceinline__ bf16x8 ld_frag(const unsigned short* p) {
    return *reinterpret_cast<const bf16x8*>(p);
}

// ---------------------------------------------------------------------------
// QKV projection: Y = X[4096,1024] @ W[1024,1024] + bias, output bf16 scattered
// into [B][H][L][DH]. blockIdx.z selects {Wq,Wk,Wv}.
// ---------------------------------------------------------------------------
__global__ __launch_bounds__(256)
void qkv_gemm_kernel(const float* __restrict__ x,
                     const float* __restrict__ Wq, const float* __restrict__ bq,
                     const float* __restrict__ Wk, const float* __restrict__ bk,
                     const float* __restrict__ Wv, const float* __restrict__ bv,
                     unsigned short* __restrict__ qkv_ws)
{
    const int which = blockIdx.z;
    const float* W    = (which == 0) ? Wq : (which == 1) ? Wk : Wv;
    const float* bias = (which == 0) ? bq : (which == 1) ? bk : bv;
    unsigned short* out = qkv_ws + (size_t)which * ((size_t)BB * HH * LL * DHH);

    __shared__ unsigned short As[64][40];
    __shared__ unsigned short Bs[64][40];

    const int tid  = threadIdx.x;
    const int lane = tid & 63;
    const int w    = tid >> 6;
    const int wr   = w >> 1, wc = w & 1;
    const int l16  = lane & 15, lk = lane >> 4;

    const int m0 = blockIdx.y * 64;
    const int n0 = blockIdx.x * 64;

    const int am  = tid >> 2, ak = (tid & 3) * 8;
    const int bkk = tid >> 3, bn = (tid & 7) * 8;

    f32x4 acc[2][2];
#pragma unroll
    for (int i = 0; i < 2; ++i)
#pragma unroll
        for (int j = 0; j < 2; ++j) acc[i][j] = f32x4{0.f, 0.f, 0.f, 0.f};

    for (int k0 = 0; k0 < DD; k0 += 32) {
        const float* ap = x + (size_t)(m0 + am) * DD + k0 + ak;
        float4 a0 = *(const float4*)ap;
        float4 a1 = *(const float4*)(ap + 4);
        const float* bp = W + (size_t)(k0 + bkk) * NH + n0 + bn;
        float4 b0 = *(const float4*)bp;
        float4 b1 = *(const float4*)(bp + 4);

        unsigned short a8[8];
        a8[0] = f2bf(a0.x); a8[1] = f2bf(a0.y); a8[2] = f2bf(a0.z); a8[3] = f2bf(a0.w);
        a8[4] = f2bf(a1.x); a8[5] = f2bf(a1.y); a8[6] = f2bf(a1.z); a8[7] = f2bf(a1.w);
        *(int4*)&As[am][ak] = *(const int4*)a8;

        Bs[bn + 0][bkk] = f2bf(b0.x); Bs[bn + 1][bkk] = f2bf(b0.y);
        Bs[bn + 2][bkk] = f2bf(b0.z); Bs[bn + 3][bkk] = f2bf(b0.w);
        Bs[bn + 4][bkk] = f2bf(b1.x); Bs[bn + 5][bkk] = f2bf(b1.y);
        Bs[bn + 6][bkk] = f2bf(b1.z); Bs[bn + 7][bkk] = f2bf(b1.w);
        __syncthreads();

        bf16x8 fa0 = ld_frag(&As[wr * 32 + l16][lk * 8]);
        bf16x8 fa1 = ld_frag(&As[wr * 32 + 16 + l16][lk * 8]);
        bf16x8 fb0 = ld_frag(&Bs[wc * 32 + l16][lk * 8]);
        bf16x8 fb1 = ld_frag(&Bs[wc * 32 + 16 + l16][lk * 8]);
        acc[0][0] = mfma_bf16(fa0, fb0, acc[0][0]);
        acc[0][1] = mfma_bf16(fa0, fb1, acc[0][1]);
        acc[1][0] = mfma_bf16(fa1, fb0, acc[1][0]);
        acc[1][1] = mfma_bf16(fa1, fb1, acc[1][1]);
        __syncthreads();
    }

#pragma unroll
    for (int fm = 0; fm < 2; ++fm)
#pragma unroll
        for (int fn = 0; fn < 2; ++fn)
#pragma unroll
            for (int r = 0; r < 4; ++r) {
                const int grow = m0 + wr * 32 + fm * 16 + lk * 4 + r;
                const int gcol = n0 + wc * 32 + fn * 16 + l16;
                const float v = acc[fm][fn][r] + bias[gcol];
                const int b = grow >> 11, i = grow & 2047;
                const int h = gcol >> 6,  d = gcol & 63;
                out[(((size_t)(b * HH + h)) * LL + i) * DHH + d] = f2bf(v);
            }
}

// ---------------------------------------------------------------------------
// Output projection: out = out_pre(bf16)[4096,1024] @ Wo + bo -> fp32 d_out
// ---------------------------------------------------------------------------
__global__ __launch_bounds__(256)
void out_gemm_kernel(const unsigned short* __restrict__ A,
                     const float* __restrict__ Wo, const float* __restrict__ bo,
                     float* __restrict__ out)
{
    __shared__ unsigned short As[64][40];
    __shared__ unsigned short Bs[64][40];

    const int tid  = threadIdx.x;
    const int lane = tid & 63;
    const int w    = tid >> 6;
    const int wr   = w >> 1, wc = w & 1;
    const int l16  = lane & 15, lk = lane >> 4;

    const int m0 = blockIdx.y * 64;
    const int n0 = blockIdx.x * 64;

    const int am  = tid >> 2, ak = (tid & 3) * 8;
    const int bkk = tid >> 3, bn = (tid & 7) * 8;

    f32x4 acc[2][2];
#pragma unroll
    for (int i = 0; i < 2; ++i)
#pragma unroll
        for (int j = 0; j < 2; ++j) acc[i][j] = f32x4{0.f, 0.f, 0.f, 0.f};

    for (int k0 = 0; k0 < NH; k0 += 32) {
        *(int4*)&As[am][ak] = *(const int4*)(A + (size_t)(m0 + am) * NH + k0 + ak);
        const float* bp = Wo + (size_t)(k0 + bkk) * DD + n0 + bn;
        float4 b0 = *(const float4*)bp;
        float4 b1 = *(const float4*)(bp + 4);
        Bs[bn + 0][bkk] = f2bf(b0.x); Bs[bn + 1][bkk] = f2bf(b0.y);
        Bs[bn + 2][bkk] = f2bf(b0.z); Bs[bn + 3][bkk] = f2bf(b0.w);
        Bs[bn + 4][bkk] = f2bf(b1.x); Bs[bn + 5][bkk] = f2bf(b1.y);
        Bs[bn + 6][bkk] = f2bf(b1.z); Bs[bn + 7][bkk] = f2bf(b1.w);
        __syncthreads();

        bf16x8 fa0 = ld_frag(&As[wr * 32 + l16][lk * 8]);
        bf16x8 fa1 = ld_frag(&As[wr * 32 + 16 + l16][lk * 8]);
        bf16x8 fb0 = ld_frag(&Bs[wc * 32 + l16][lk * 8]);
        bf16x8 fb1 = ld_frag(&Bs[wc * 32 + 16 + l16][lk * 8]);
        acc[0][0] = mfma_bf16(fa0, fb0, acc[0][0]);
        acc[0][1] = mfma_bf16(fa0, fb1, acc[0][1]);
        acc[1][0] = mfma_bf16(fa1, fb0, acc[1][0]);
        acc[1][1] = mfma_bf16(fa1, fb1, acc[1][1]);
        __syncthreads();
    }

#pragma unroll
    for (int fm = 0; fm < 2; ++fm)
#pragma unroll
        for (int fn = 0; fn < 2; ++fn)
#pragma unroll
            for (int r = 0; r < 4; ++r) {
                const int grow = m0 + wr * 32 + fm * 16 + lk * 4 + r;
                const int gcol = n0 + wc * 32 + fn * 16 + l16;
                out[(size_t)grow * DD + gcol] = acc[fm][fn][r] + bo[gcol];
            }
}

// ---------------------------------------------------------------------------
// Attention pass A (stats): softmax denominators only. No LDS; low VGPR;
// 8 waves/SIMD target. Each block: 32 q-rows x HALF of the causal j-range
// (4096 blocks total). Partial sums -> s_part[2][B*H*L] (deterministic).
// ---------------------------------------------------------------------------
__global__ __launch_bounds__(128, 8)
void attn_stats_kernel(const unsigned short* __restrict__ qws,
                       const unsigned short* __restrict__ kws,
                       const float* __restrict__ B_graph,
                       const float* __restrict__ lattice,
                       const float* __restrict__ Wl,
                       const float* __restrict__ bl,
                       float* __restrict__ s_part)
{
    const int n    = blockIdx.x;         // [0, 4096)
    const int half = n & 1;
    const int m    = n >> 1;             // [0, 2048)
    const int bh = m & 31;
    const int tb = m >> 5;
    const int kg = tb >> 3, tt = tb & 7;
    const int ib = 8 * kg + ((kg & 1) ? 7 - tt : tt);
    const int b = bh >> 4, h = bh & 15;
    const int i0 = ib * 32;
    const int nj = (ib >> 1) + 1;
    const int j0 = half ? (nj >> 1) : 0;
    const int j1 = half ? nj : (nj >> 1);

    const int tid  = threadIdx.x;
    const int lane = tid & 63;
    const int w    = tid >> 6;
    const int l16  = lane & 15, lk = lane >> 4;

    float lb = bl[h];
#pragma unroll
    for (int t = 0; t < 6; ++t) lb += lattice[b * 6 + t] * Wl[t * HH + h];

    const int bhh = b * HH + h;
    const unsigned short* qbase = qws + ((size_t)bhh * LL + i0) * DHH;
    const unsigned short* kbase = kws + (size_t)bhh * LL * DHH;
    const float* gb = B_graph + (size_t)b * LL * LL;

    bf16x8 qa0 = ld_frag(qbase + (size_t)(w * 16 + l16) * DHH + lk * 8);
    bf16x8 qa1 = ld_frag(qbase + (size_t)(w * 16 + l16) * DHH + 32 + lk * 8);

    const int gi0 = i0 + w * 16 + lk * 4;  // + r

    float s_run[4];
#pragma unroll
    for (int r = 0; r < 4; ++r) s_run[r] = 0.f;

    for (int jb = j0; jb < j1; ++jb) {
        const unsigned short* kt = kbase + (size_t)jb * 64 * DHH;
#pragma unroll
        for (int fn = 0; fn < 4; ++fn) {
            bf16x8 kb0 = ld_frag(kt + (size_t)(fn * 16 + l16) * DHH + lk * 8);
            bf16x8 kb1 = ld_frag(kt + (size_t)(fn * 16 + l16) * DHH + 32 + lk * 8);
            f32x4 z = {0.f, 0.f, 0.f, 0.f};
            z = mfma_bf16(qa0, kb0, z);
            z = mfma_bf16(qa1, kb1, z);
            const int gj = jb * 64 + fn * 16 + l16;
#pragma unroll
            for (int r = 0; r < 4; ++r) {
                const int gi = gi0 + r;
                const float sv = fmaf(z[r], 0.125f, lb + gb[(size_t)gi * LL + gj]);
                s_run[r] += (gj > gi) ? 0.f : __expf(sv);
            }
        }
    }
#pragma unroll
    for (int off = 1; off < 16; off <<= 1)
#pragma unroll
        for (int r = 0; r < 4; ++r) s_run[r] += __shfl_xor(s_run[r], off, 64);

    if (l16 == 0) {
        float* sp = s_part + (size_t)half * (BB * HH * LL) + (size_t)bhh * LL + gi0;
#pragma unroll
        for (int r = 0; r < 4; ++r) sp[r] = s_run[r];
    }
}

// ---------------------------------------------------------------------------
// Attention pass B (write): recompute S, normalize with inv_s from s_part,
// coalesced NT attn store via LDS readback, PV accumulate, out_pre write.
// ---------------------------------------------------------------------------
__global__ __launch_bounds__(128)
void attn_write_kernel(const unsigned short* __restrict__ qws,
                       const unsigned short* __restrict__ kws,
                       const unsigned short* __restrict__ vws,
                       const float* __restrict__ B_graph,
                       const float* __restrict__ lattice,
                       const float* __restrict__ Wl,
                       const float* __restrict__ bl,
                       const float* __restrict__ s_part,
                       float* __restrict__ attn_out,
                       unsigned short* __restrict__ out_pre)
{
    const int n  = blockIdx.x;           // [0, 2048)
    const int bh = n & 31;
    const int tb = n >> 5;               // [0, 64)
    const int kg = tb >> 3, tt = tb & 7;
    const int ib = 8 * kg + ((kg & 1) ? 7 - tt : tt);
    const int b = bh >> 4, h = bh & 15;
    const int i0 = ib * 32;
    const int nj = (ib >> 1) + 1;

    __shared__ unsigned short Vs[64][72];     // V^T: [d][j], +8 pad
    __shared__ unsigned short Ps[2][16][72];  // per-wave P tile [row][j]

    const int tid  = threadIdx.x;
    const int lane = tid & 63;
    const int w    = tid >> 6;           // 0..1
    const int l16  = lane & 15, lk = lane >> 4;

    float lb = bl[h];
#pragma unroll
    for (int t = 0; t < 6; ++t) lb += lattice[b * 6 + t] * Wl[t * HH + h];

    const int bhh = b * HH + h;
    const unsigned short* qbase = qws + ((size_t)bhh * LL + i0) * DHH;
    const unsigned short* kbase = kws + (size_t)bhh * LL * DHH;
    const unsigned short* vbase = vws + (size_t)bhh * LL * DHH;
    const float* gb = B_graph + (size_t)b * LL * LL;

    bf16x8 qa0 = ld_frag(qbase + (size_t)(w * 16 + l16) * DHH + lk * 8);
    bf16x8 qa1 = ld_frag(qbase + (size_t)(w * 16 + l16) * DHH + 32 + lk * 8);

    const int gi0 = i0 + w * 16 + lk * 4;  // + r

    float inv_s[4];
    {
        const float* s0 = s_part + (size_t)bhh * LL + gi0;
        const float* s1 = s0 + (size_t)(BB * HH * LL);
#pragma unroll
        for (int r = 0; r < 4; ++r) inv_s[r] = 1.0f / (s0[r] + s1[r]);
    }

    f32x4 oacc[4];
#pragma unroll
    for (int fn = 0; fn < 4; ++fn) oacc[fn] = f32x4{0.f, 0.f, 0.f, 0.f};

    for (int jb = 0; jb < nj; ++jb) {
        bf16x8 kb[8];
        {
            const unsigned short* kt = kbase + (size_t)jb * 64 * DHH;
#pragma unroll
            for (int fn = 0; fn < 4; ++fn) {
                kb[2 * fn]     = ld_frag(kt + (size_t)(fn * 16 + l16) * DHH + lk * 8);
                kb[2 * fn + 1] = ld_frag(kt + (size_t)(fn * 16 + l16) * DHH + 32 + lk * 8);
            }
        }

        {   // stage V transposed into LDS: 128 threads, 64 rows x 2 col-halves
            const int r = tid >> 1, c0 = (tid & 1) * 32;
            const unsigned short* vp = vbase + ((size_t)(jb * 64 + r)) * DHH + c0;
            unsigned short tmp[32];
            *(int4*)&tmp[0]  = *(const int4*)vp;
            *(int4*)&tmp[8]  = *(const int4*)(vp + 8);
            *(int4*)&tmp[16] = *(const int4*)(vp + 16);
            *(int4*)&tmp[24] = *(const int4*)(vp + 24);
#pragma unroll
            for (int m2 = 0; m2 < 32; ++m2) Vs[c0 + m2][r] = tmp[m2];
        }
        __syncthreads();

#pragma unroll
        for (int fn = 0; fn < 4; ++fn) {
            f32x4 z = {0.f, 0.f, 0.f, 0.f};
            z = mfma_bf16(qa0, kb[2 * fn], z);
            z = mfma_bf16(qa1, kb[2 * fn + 1], z);
            const int gj = jb * 64 + fn * 16 + l16;
#pragma unroll
            for (int r = 0; r < 4; ++r) {
                const int gi = gi0 + r;
                const float sv = fmaf(z[r], 0.125f, lb + gb[(size_t)gi * LL + gj]);
                const float p = ((gj > gi) ? 0.f : __expf(sv)) * inv_s[r];
                Ps[w][lk * 4 + r][fn * 16 + l16] = f2bf(p);
            }
        }
        __syncthreads();

        // coalesced attn store: each wave reads back its own 16x64 P tile
        const int jc0 = jb * 64 + l16 * 4;
#pragma unroll
        for (int s = 0; s < 4; ++s) {
            const int row = s * 4 + lk;          // 0..15
            const int gi  = i0 + w * 16 + row;
            const unsigned short* pp = &Ps[w][row][l16 * 4];
            ushort4 pb = *(const ushort4*)pp;
            f32x4 pv;
            pv.x = bf2f(pb.x); pv.y = bf2f(pb.y);
            pv.z = bf2f(pb.z); pv.w = bf2f(pb.w);
            __builtin_nontemporal_store(
                pv, (f32x4*)&attn_out[((size_t)bhh * LL + gi) * LL + jc0]);
        }

        bf16x8 pa0 = ld_frag(&Ps[w][l16][lk * 8]);
        bf16x8 pa1 = ld_frag(&Ps[w][l16][32 + lk * 8]);
#pragma unroll
        for (int fn = 0; fn < 4; ++fn) {
            bf16x8 vb0 = ld_frag(&Vs[fn * 16 + l16][lk * 8]);
            bf16x8 vb1 = ld_frag(&Vs[fn * 16 + l16][32 + lk * 8]);
            oacc[fn] = mfma_bf16(pa0, vb0, oacc[fn]);
            oacc[fn] = mfma_bf16(pa1, vb1, oacc[fn]);
        }
        __syncthreads();
    }

    // zero-fill strictly-upper column blocks (cols >= nj*64) for our 32 rows
    const int zc0 = nj * 64;
    if (zc0 < LL) {
        const int nz4 = (LL - zc0) >> 2;
        const f32x4 z4 = {0.f, 0.f, 0.f, 0.f};
        for (int row = 0; row < 32; ++row) {
            f32x4* zp = (f32x4*)(attn_out + ((size_t)bhh * LL + i0 + row) * LL + zc0);
            for (int c4 = tid; c4 < nz4; c4 += 128)
                __builtin_nontemporal_store(z4, &zp[c4]);
        }
    }

    // write O to out_pre [B][L][H*DH] (bf16)
#pragma unroll
    for (int fn = 0; fn < 4; ++fn)
#pragma unroll
        for (int r = 0; r < 4; ++r) {
            const int gi = gi0 + r;
            const int d  = fn * 16 + l16;
            out_pre[((size_t)(b * LL + gi)) * NH + h * DHH + d] = f2bf(oacc[fn][r]);
        }
}

// ---------------------------------------------------------------------------
extern "C" void kernel_launch(void* const* d_in, const int* in_sizes, int n_in,
                              void* d_out, int out_size, void* d_ws, size_t ws_size,
                              hipStream_t stream)
{
    const float* x       = (const float*)d_in[0];
    const float* lattice = (const float*)d_in[1];
    const float* B_graph = (const float*)d_in[2];
    const float* Wq = (const float*)d_in[4];
    const float* bq = (const float*)d_in[5];
    const float* Wk = (const float*)d_in[6];
    const float* bk = (const float*)d_in[7];
    const float* Wv = (const float*)d_in[8];
    const float* bv = (const float*)d_in[9];
    const float* Wo = (const float*)d_in[10];
    const float* bo = (const float*)d_in[11];
    const float* Wl = (const float*)d_in[12];
    const float* bl = (const float*)d_in[13];

    float* out  = (float*)d_out;
    float* attn = out + (size_t)BB * LL * DD;

    unsigned short* qkv    = (unsigned short*)d_ws;
    unsigned short* qw     = qkv;
    unsigned short* kw     = qkv + (size_t)BB * HH * LL * DHH;
    unsigned short* vw     = qkv + (size_t)2 * BB * HH * LL * DHH;
    unsigned short* outpre = qkv + (size_t)3 * BB * HH * LL * DHH;
    float*          s_part = (float*)(outpre + (size_t)BB * LL * NH);  // 2 x B*H*L

    dim3 g1(NH / 64, (BB * LL) / 64, 3);
    qkv_gemm_kernel<<<g1, 256, 0, stream>>>(x, Wq, bq, Wk, bk, Wv, bv, qkv);

    attn_stats_kernel<<<dim3(2 * BB * HH * (LL / 32)), 128, 0, stream>>>(
        qw, kw, B_graph, lattice, Wl, bl, s_part);

    attn_write_kernel<<<dim3(BB * HH * (LL / 32)), 128, 0, stream>>>(
        qw, kw, vw, B_graph, lattice, Wl, bl, s_part, attn, outpre);

    dim3 g3(DD / 64, (BB * LL) / 64, 1);
    out_gemm_kernel<<<g3, 256, 0, stream>>>(outpre, Wo, bo, out);
}

// Round 7
// 421.753 us; speedup vs baseline: 1.0606x; 1.0606x over previous
//
#include <hip/hip_runtime.h>
#include <stdint.h>
#include <stddef.h>

#define BB 2
#define LL 2048
#define DD 1024
#define HH 16
#define DHH 64
#define NH 1024  // H*DH

typedef __attribute__((ext_vector_type(8))) __bf16 bf16x8;
typedef __attribute__((ext_vector_type(4))) float f32x4;

__device__ __forceinline__ f32x4 mfma_bf16(bf16x8 a, bf16x8 b, f32x4 c) {
    return __builtin_amdgcn_mfma_f32_16x16x32_bf16(a, b, c, 0, 0, 0);
}

__device__ __forceinline__ unsigned short f2bf(float f) {
    union { float f; unsigned u; } v; v.f = f;
    unsigned r = v.u + 0x7FFFu + ((v.u >> 16) & 1u);  // RNE
    return (unsigned short)(r >> 16);
}

__device__ __forceinline__ float bf2f(unsigned short s) {
    union { unsigned u; float f; } v; v.u = ((unsigned)s) << 16;
    return v.f;
}

__device__ __forceinline__ bf16x8 ld_frag(const unsigned short* p) {
    return *reinterpret_cast<const bf16x8*>(p);
}

// ---------------------------------------------------------------------------
// QKV projection: Y = X[4096,1024] @ W[1024,1024] + bias, output bf16 scattered
// into [B][H][L][DH]. blockIdx.z selects {Wq,Wk,Wv}.
// ---------------------------------------------------------------------------
__global__ __launch_bounds__(256)
void qkv_gemm_kernel(const float* __restrict__ x,
                     const float* __restrict__ Wq, const float* __restrict__ bq,
                     const float* __restrict__ Wk, const float* __restrict__ bk,
                     const float* __restrict__ Wv, const float* __restrict__ bv,
                     unsigned short* __restrict__ qkv_ws)
{
    const int which = blockIdx.z;
    const float* W    = (which == 0) ? Wq : (which == 1) ? Wk : Wv;
    const float* bias = (which == 0) ? bq : (which == 1) ? bk : bv;
    unsigned short* out = qkv_ws + (size_t)which * ((size_t)BB * HH * LL * DHH);

    __shared__ unsigned short As[64][40];
    __shared__ unsigned short Bs[64][40];

    const int tid  = threadIdx.x;
    const int lane = tid & 63;
    const int w    = tid >> 6;
    const int wr   = w >> 1, wc = w & 1;
    const int l16  = lane & 15, lk = lane >> 4;

    const int m0 = blockIdx.y * 64;
    const int n0 = blockIdx.x * 64;

    const int am  = tid >> 2, ak = (tid & 3) * 8;
    const int bkk = tid >> 3, bn = (tid & 7) * 8;

    f32x4 acc[2][2];
#pragma unroll
    for (int i = 0; i < 2; ++i)
#pragma unroll
        for (int j = 0; j < 2; ++j) acc[i][j] = f32x4{0.f, 0.f, 0.f, 0.f};

    for (int k0 = 0; k0 < DD; k0 += 32) {
        const float* ap = x + (size_t)(m0 + am) * DD + k0 + ak;
        float4 a0 = *(const float4*)ap;
        float4 a1 = *(const float4*)(ap + 4);
        const float* bp = W + (size_t)(k0 + bkk) * NH + n0 + bn;
        float4 b0 = *(const float4*)bp;
        float4 b1 = *(const float4*)(bp + 4);

        unsigned short a8[8];
        a8[0] = f2bf(a0.x); a8[1] = f2bf(a0.y); a8[2] = f2bf(a0.z); a8[3] = f2bf(a0.w);
        a8[4] = f2bf(a1.x); a8[5] = f2bf(a1.y); a8[6] = f2bf(a1.z); a8[7] = f2bf(a1.w);
        *(int4*)&As[am][ak] = *(const int4*)a8;

        Bs[bn + 0][bkk] = f2bf(b0.x); Bs[bn + 1][bkk] = f2bf(b0.y);
        Bs[bn + 2][bkk] = f2bf(b0.z); Bs[bn + 3][bkk] = f2bf(b0.w);
        Bs[bn + 4][bkk] = f2bf(b1.x); Bs[bn + 5][bkk] = f2bf(b1.y);
        Bs[bn + 6][bkk] = f2bf(b1.z); Bs[bn + 7][bkk] = f2bf(b1.w);
        __syncthreads();

        bf16x8 fa0 = ld_frag(&As[wr * 32 + l16][lk * 8]);
        bf16x8 fa1 = ld_frag(&As[wr * 32 + 16 + l16][lk * 8]);
        bf16x8 fb0 = ld_frag(&Bs[wc * 32 + l16][lk * 8]);
        bf16x8 fb1 = ld_frag(&Bs[wc * 32 + 16 + l16][lk * 8]);
        acc[0][0] = mfma_bf16(fa0, fb0, acc[0][0]);
        acc[0][1] = mfma_bf16(fa0, fb1, acc[0][1]);
        acc[1][0] = mfma_bf16(fa1, fb0, acc[1][0]);
        acc[1][1] = mfma_bf16(fa1, fb1, acc[1][1]);
        __syncthreads();
    }

#pragma unroll
    for (int fm = 0; fm < 2; ++fm)
#pragma unroll
        for (int fn = 0; fn < 2; ++fn)
#pragma unroll
            for (int r = 0; r < 4; ++r) {
                const int grow = m0 + wr * 32 + fm * 16 + lk * 4 + r;
                const int gcol = n0 + wc * 32 + fn * 16 + l16;
                const float v = acc[fm][fn][r] + bias[gcol];
                const int b = grow >> 11, i = grow & 2047;
                const int h = gcol >> 6,  d = gcol & 63;
                out[(((size_t)(b * HH + h)) * LL + i) * DHH + d] = f2bf(v);
            }
}

// ---------------------------------------------------------------------------
// V transpose: vws [bh][l][d] -> vT [bh][d][l]. 64x64 tiles, 256 threads.
// ---------------------------------------------------------------------------
__global__ __launch_bounds__(256)
void v_transpose_kernel(const unsigned short* __restrict__ vws,
                        unsigned short* __restrict__ vT)
{
    __shared__ unsigned short Ls[64][72];
    const int bh = blockIdx.y;
    const int i0 = blockIdx.x * 64;
    const int tid = threadIdx.x;

    // load: row i = tid>>2, cols (tid&3)*16 .. +15 (coalesced 32B)
    {
        const int r = tid >> 2, c = (tid & 3) * 16;
        const unsigned short* vp = vws + ((size_t)bh * LL + i0 + r) * DHH + c;
        *(int4*)&Ls[r][c]     = *(const int4*)vp;
        *(int4*)&Ls[r][c + 8] = *(const int4*)(vp + 8);
    }
    __syncthreads();

    // store: row d = tid>>2, i-chunk (tid&3)*16 .. +15
    {
        const int d = tid >> 2, c = (tid & 3) * 16;
        unsigned short tmp[16];
#pragma unroll
        for (int m = 0; m < 16; ++m) tmp[m] = Ls[c + m][d];
        unsigned short* op = vT + ((size_t)bh * DHH + d) * LL + i0 + c;
        *(int4*)op       = *(const int4*)&tmp[0];
        *(int4*)(op + 8) = *(const int4*)&tmp[8];
    }
}

// ---------------------------------------------------------------------------
// Fused causal attention. QBLK=32 rows per block, 128 threads (2 waves),
// ZERO barriers: waves share nothing (V comes transposed from global, Ps is
// per-wave). Balanced grid: ib = 8*kg + (kg odd ? 7-t : t). Max-free softmax
// (scores bounded). Pass A: denominators. Pass B: recompute S, normalize,
// coalesced NT attn store via per-wave Ps readback, PV with V^T global frags.
// ---------------------------------------------------------------------------
__global__ __launch_bounds__(128, 4)
void attn_kernel(const unsigned short* __restrict__ qws,
                 const unsigned short* __restrict__ kws,
                 const unsigned short* __restrict__ vT,
                 const float* __restrict__ B_graph,
                 const float* __restrict__ lattice,
                 const float* __restrict__ Wl,
                 const float* __restrict__ bl,
                 float* __restrict__ attn_out,
                 unsigned short* __restrict__ out_pre)
{
    const int n  = blockIdx.x;           // [0, 2048)
    const int bh = n & 31;
    const int tb = n >> 5;               // [0, 64)
    const int kg = tb >> 3, tt = tb & 7;
    const int ib = 8 * kg + ((kg & 1) ? 7 - tt : tt);
    const int b = bh >> 4, h = bh & 15;
    const int i0 = ib * 32;
    const int nj = (ib >> 1) + 1;        // number of 64-col j tiles

    __shared__ unsigned short Ps[2][16][72];  // per-wave P tile [row][j]

    const int tid  = threadIdx.x;
    const int lane = tid & 63;
    const int w    = tid >> 6;           // 0..1
    const int l16  = lane & 15, lk = lane >> 4;

    float lb = bl[h];
#pragma unroll
    for (int t = 0; t < 6; ++t) lb += lattice[b * 6 + t] * Wl[t * HH + h];

    const int bhh = b * HH + h;
    const unsigned short* qbase = qws + ((size_t)bhh * LL + i0) * DHH;
    const unsigned short* kbase = kws + (size_t)bhh * LL * DHH;
    const unsigned short* vtb   = vT + (size_t)bhh * DHH * LL;
    const float* gb = B_graph + (size_t)b * LL * LL;

    bf16x8 qa0 = ld_frag(qbase + (size_t)(w * 16 + l16) * DHH + lk * 8);
    bf16x8 qa1 = ld_frag(qbase + (size_t)(w * 16 + l16) * DHH + 32 + lk * 8);

    const int gi0 = i0 + w * 16 + lk * 4;  // + r

    float s_run[4];
#pragma unroll
    for (int r = 0; r < 4; ++r) s_run[r] = 0.f;

    auto loadK = [&](int jb, bf16x8* kb) {
        const unsigned short* kt = kbase + (size_t)jb * 64 * DHH;
#pragma unroll
        for (int fn = 0; fn < 4; ++fn) {
            kb[2 * fn]     = ld_frag(kt + (size_t)(fn * 16 + l16) * DHH + lk * 8);
            kb[2 * fn + 1] = ld_frag(kt + (size_t)(fn * 16 + l16) * DHH + 32 + lk * 8);
        }
    };

    auto accumTile = [&](int jb, const bf16x8* kb) {
#pragma unroll
        for (int fn = 0; fn < 4; ++fn) {
            f32x4 z = {0.f, 0.f, 0.f, 0.f};
            z = mfma_bf16(qa0, kb[2 * fn], z);
            z = mfma_bf16(qa1, kb[2 * fn + 1], z);
            const int gj = jb * 64 + fn * 16 + l16;
#pragma unroll
            for (int r = 0; r < 4; ++r) {
                const int gi = gi0 + r;
                const float sv = fmaf(z[r], 0.125f, lb + gb[(size_t)gi * LL + gj]);
                s_run[r] += (gj > gi) ? 0.f : __expf(sv);
            }
        }
    };

    // -------- pass A: denominators --------
    {
        int jb = 0;
        for (; jb + 2 <= nj; jb += 2) {
            bf16x8 k0[8], k1[8];
            loadK(jb, k0);
            loadK(jb + 1, k1);
            accumTile(jb, k0);
            accumTile(jb + 1, k1);
        }
        if (jb < nj) {
            bf16x8 k0[8];
            loadK(jb, k0);
            accumTile(jb, k0);
        }
    }
#pragma unroll
    for (int off = 1; off < 16; off <<= 1)
#pragma unroll
        for (int r = 0; r < 4; ++r) s_run[r] += __shfl_xor(s_run[r], off, 64);

    float inv_s[4];
#pragma unroll
    for (int r = 0; r < 4; ++r) inv_s[r] = 1.0f / s_run[r];

    f32x4 oacc[4];
#pragma unroll
    for (int fn = 0; fn < 4; ++fn) oacc[fn] = f32x4{0.f, 0.f, 0.f, 0.f};

    // -------- pass B: attn write + PV (no barriers) --------
    for (int jb = 0; jb < nj; ++jb) {
        bf16x8 kb[8];
        loadK(jb, kb);

#pragma unroll
        for (int fn = 0; fn < 4; ++fn) {
            f32x4 z = {0.f, 0.f, 0.f, 0.f};
            z = mfma_bf16(qa0, kb[2 * fn], z);
            z = mfma_bf16(qa1, kb[2 * fn + 1], z);
            const int gj = jb * 64 + fn * 16 + l16;
#pragma unroll
            for (int r = 0; r < 4; ++r) {
                const int gi = gi0 + r;
                const float sv = fmaf(z[r], 0.125f, lb + gb[(size_t)gi * LL + gj]);
                const float p = ((gj > gi) ? 0.f : __expf(sv)) * inv_s[r];
                Ps[w][lk * 4 + r][fn * 16 + l16] = f2bf(p);
            }
        }
        // intra-wave ds_write -> ds_read: ordered by lgkmcnt, no barrier needed

        // coalesced attn store: wave reads back its own 16x64 P tile
        const int jc0 = jb * 64 + l16 * 4;
#pragma unroll
        for (int s = 0; s < 4; ++s) {
            const int row = s * 4 + lk;          // 0..15
            const int gi  = i0 + w * 16 + row;
            const unsigned short* pp = &Ps[w][row][l16 * 4];
            ushort4 pb = *(const ushort4*)pp;
            f32x4 pv;
            pv.x = bf2f(pb.x); pv.y = bf2f(pb.y);
            pv.z = bf2f(pb.z); pv.w = bf2f(pb.w);
            __builtin_nontemporal_store(
                pv, (f32x4*)&attn_out[((size_t)bhh * LL + gi) * LL + jc0]);
        }

        bf16x8 pa0 = ld_frag(&Ps[w][l16][lk * 8]);
        bf16x8 pa1 = ld_frag(&Ps[w][l16][32 + lk * 8]);
#pragma unroll
        for (int fn = 0; fn < 4; ++fn) {
            const unsigned short* vp = vtb + (size_t)(fn * 16 + l16) * LL + jb * 64;
            bf16x8 vb0 = ld_frag(vp + lk * 8);
            bf16x8 vb1 = ld_frag(vp + 32 + lk * 8);
            oacc[fn] = mfma_bf16(pa0, vb0, oacc[fn]);
            oacc[fn] = mfma_bf16(pa1, vb1, oacc[fn]);
        }
    }

    // zero-fill strictly-upper column blocks (cols >= nj*64) for our 32 rows
    const int zc0 = nj * 64;
    if (zc0 < LL) {
        const int nz4 = (LL - zc0) >> 2;
        const f32x4 z4 = {0.f, 0.f, 0.f, 0.f};
        for (int row = 0; row < 32; ++row) {
            f32x4* zp = (f32x4*)(attn_out + ((size_t)bhh * LL + i0 + row) * LL + zc0);
            for (int c4 = tid; c4 < nz4; c4 += 128)
                __builtin_nontemporal_store(z4, &zp[c4]);
        }
    }

    // write O to out_pre [B][L][H*DH] (bf16)
#pragma unroll
    for (int fn = 0; fn < 4; ++fn)
#pragma unroll
        for (int r = 0; r < 4; ++r) {
            const int gi = gi0 + r;
            const int d  = fn * 16 + l16;
            out_pre[((size_t)(b * LL + gi)) * NH + h * DHH + d] = f2bf(oacc[fn][r]);
        }
}

// ---------------------------------------------------------------------------
// Output projection: out = out_pre(bf16)[4096,1024] @ Wo + bo -> fp32 d_out
// ---------------------------------------------------------------------------
__global__ __launch_bounds__(256)
void out_gemm_kernel(const unsigned short* __restrict__ A,
                     const float* __restrict__ Wo, const float* __restrict__ bo,
                     float* __restrict__ out)
{
    __shared__ unsigned short As[64][40];
    __shared__ unsigned short Bs[64][40];

    const int tid  = threadIdx.x;
    const int lane = tid & 63;
    const int w    = tid >> 6;
    const int wr   = w >> 1, wc = w & 1;
    const int l16  = lane & 15, lk = lane >> 4;

    const int m0 = blockIdx.y * 64;
    const int n0 = blockIdx.x * 64;

    const int am  = tid >> 2, ak = (tid & 3) * 8;
    const int bkk = tid >> 3, bn = (tid & 7) * 8;

    f32x4 acc[2][2];
#pragma unroll
    for (int i = 0; i < 2; ++i)
#pragma unroll
        for (int j = 0; j < 2; ++j) acc[i][j] = f32x4{0.f, 0.f, 0.f, 0.f};

    for (int k0 = 0; k0 < NH; k0 += 32) {
        *(int4*)&As[am][ak] = *(const int4*)(A + (size_t)(m0 + am) * NH + k0 + ak);
        const float* bp = Wo + (size_t)(k0 + bkk) * DD + n0 + bn;
        float4 b0 = *(const float4*)bp;
        float4 b1 = *(const float4*)(bp + 4);
        Bs[bn + 0][bkk] = f2bf(b0.x); Bs[bn + 1][bkk] = f2bf(b0.y);
        Bs[bn + 2][bkk] = f2bf(b0.z); Bs[bn + 3][bkk] = f2bf(b0.w);
        Bs[bn + 4][bkk] = f2bf(b1.x); Bs[bn + 5][bkk] = f2bf(b1.y);
        Bs[bn + 6][bkk] = f2bf(b1.z); Bs[bn + 7][bkk] = f2bf(b1.w);
        __syncthreads();

        bf16x8 fa0 = ld_frag(&As[wr * 32 + l16][lk * 8]);
        bf16x8 fa1 = ld_frag(&As[wr * 32 + 16 + l16][lk * 8]);
        bf16x8 fb0 = ld_frag(&Bs[wc * 32 + l16][lk * 8]);
        bf16x8 fb1 = ld_frag(&Bs[wc * 32 + 16 + l16][lk * 8]);
        acc[0][0] = mfma_bf16(fa0, fb0, acc[0][0]);
        acc[0][1] = mfma_bf16(fa0, fb1, acc[0][1]);
        acc[1][0] = mfma_bf16(fa1, fb0, acc[1][0]);
        acc[1][1] = mfma_bf16(fa1, fb1, acc[1][1]);
        __syncthreads();
    }

#pragma unroll
    for (int fm = 0; fm < 2; ++fm)
#pragma unroll
        for (int fn = 0; fn < 2; ++fn)
#pragma unroll
            for (int r = 0; r < 4; ++r) {
                const int grow = m0 + wr * 32 + fm * 16 + lk * 4 + r;
                const int gcol = n0 + wc * 32 + fn * 16 + l16;
                out[(size_t)grow * DD + gcol] = acc[fm][fn][r] + bo[gcol];
            }
}

// ---------------------------------------------------------------------------
extern "C" void kernel_launch(void* const* d_in, const int* in_sizes, int n_in,
                              void* d_out, int out_size, void* d_ws, size_t ws_size,
                              hipStream_t stream)
{
    const float* x       = (const float*)d_in[0];
    const float* lattice = (const float*)d_in[1];
    const float* B_graph = (const float*)d_in[2];
    const float* Wq = (const float*)d_in[4];
    const float* bq = (const float*)d_in[5];
    const float* Wk = (const float*)d_in[6];
    const float* bk = (const float*)d_in[7];
    const float* Wv = (const float*)d_in[8];
    const float* bv = (const float*)d_in[9];
    const float* Wo = (const float*)d_in[10];
    const float* bo = (const float*)d_in[11];
    const float* Wl = (const float*)d_in[12];
    const float* bl = (const float*)d_in[13];

    float* out  = (float*)d_out;
    float* attn = out + (size_t)BB * LL * DD;

    const size_t PHL = (size_t)BB * HH * LL * DHH;   // per-tensor bf16 elems
    unsigned short* qkv    = (unsigned short*)d_ws;
    unsigned short* qw     = qkv;
    unsigned short* kw     = qkv + PHL;
    unsigned short* vw     = qkv + 2 * PHL;
    unsigned short* outpre = qkv + 3 * PHL;          // [B][L][NH]
    unsigned short* vT     = outpre + (size_t)BB * LL * NH;  // [bh][d][l]

    dim3 g1(NH / 64, (BB * LL) / 64, 3);
    qkv_gemm_kernel<<<g1, 256, 0, stream>>>(x, Wq, bq, Wk, bk, Wv, bv, qkv);

    v_transpose_kernel<<<dim3(LL / 64, BB * HH), 256, 0, stream>>>(vw, vT);

    attn_kernel<<<dim3(BB * HH * (LL / 32)), 128, 0, stream>>>(
        qw, kw, vT, B_graph, lattice, Wl, bl, attn, outpre);

    dim3 g3(DD / 64, (BB * LL) / 64, 1);
    out_gemm_kernel<<<g3, 256, 0, stream>>>(outpre, Wo, bo, out);
}

// Round 8
// 330.390 us; speedup vs baseline: 1.3539x; 1.2765x over previous
//
#include <hip/hip_runtime.h>
#include <stdint.h>
#include <stddef.h>

#define BB 2
#define LL 2048
#define DD 1024
#define HH 16
#define DHH 64
#define NH 1024  // H*DH

typedef __attribute__((ext_vector_type(8))) __bf16 bf16x8;
typedef __attribute__((ext_vector_type(4))) float f32x4;

__device__ __forceinline__ f32x4 mfma_bf16(bf16x8 a, bf16x8 b, f32x4 c) {
    return __builtin_amdgcn_mfma_f32_16x16x32_bf16(a, b, c, 0, 0, 0);
}

__device__ __forceinline__ unsigned short f2bf(float f) {
    union { float f; unsigned u; } v; v.f = f;
    unsigned r = v.u + 0x7FFFu + ((v.u >> 16) & 1u);  // RNE
    return (unsigned short)(r >> 16);
}

__device__ __forceinline__ float bf2f(unsigned short s) {
    union { unsigned u; float f; } v; v.u = ((unsigned)s) << 16;
    return v.f;
}

__device__ __forceinline__ bf16x8 ld_frag(const unsigned short* p) {
    return *reinterpret_cast<const bf16x8*>(p);
}

// ---------------------------------------------------------------------------
// x [4096][1024] fp32 -> bf16 flat.
// ---------------------------------------------------------------------------
__global__ __launch_bounds__(256)
void conv_x_kernel(const float* __restrict__ x, unsigned short* __restrict__ xb)
{
    const size_t i = ((size_t)blockIdx.x * 256 + threadIdx.x) * 8;
    float4 a = *(const float4*)(x + i);
    float4 b = *(const float4*)(x + i + 4);
    unsigned short t[8];
    t[0] = f2bf(a.x); t[1] = f2bf(a.y); t[2] = f2bf(a.z); t[3] = f2bf(a.w);
    t[4] = f2bf(b.x); t[5] = f2bf(b.y); t[6] = f2bf(b.z); t[7] = f2bf(b.w);
    *(int4*)(xb + i) = *(const int4*)t;
}

// ---------------------------------------------------------------------------
// W [K=1024][N=1024] fp32 -> W^T [N][K] bf16. blockIdx.z selects Wq/Wk/Wv/Wo.
// which 0..2 -> Wqkvt + which*1M ; which 3 -> Wot.
// ---------------------------------------------------------------------------
__global__ __launch_bounds__(256)
void conv_w_kernel(const float* __restrict__ W0, const float* __restrict__ W1,
                   const float* __restrict__ W2, const float* __restrict__ W3,
                   unsigned short* __restrict__ Wqkvt,
                   unsigned short* __restrict__ Wot)
{
    __shared__ unsigned short Ls[64][72];
    const int which = blockIdx.z;
    const float* W = (which == 0) ? W0 : (which == 1) ? W1 : (which == 2) ? W2 : W3;
    unsigned short* Wt = (which == 3) ? Wot : (Wqkvt + (size_t)which * 1024 * 1024);

    const int kt = blockIdx.x * 64, nt = blockIdx.y * 64;
    const int tid = threadIdx.x;

    {   // load 64(k) x 64(n) fp32, convert, store to LDS
        const int r = tid >> 2, c = (tid & 3) * 16;
        const float* wp = W + (size_t)(kt + r) * 1024 + nt + c;
        unsigned short t[16];
#pragma unroll
        for (int q = 0; q < 4; ++q) {
            float4 f = *(const float4*)(wp + q * 4);
            t[q * 4 + 0] = f2bf(f.x); t[q * 4 + 1] = f2bf(f.y);
            t[q * 4 + 2] = f2bf(f.z); t[q * 4 + 3] = f2bf(f.w);
        }
        *(int4*)&Ls[r][c]     = *(const int4*)&t[0];
        *(int4*)&Ls[r][c + 8] = *(const int4*)&t[8];
    }
    __syncthreads();
    {   // write transposed: row n, cols k
        const int nr = tid >> 2, kc = (tid & 3) * 16;
        unsigned short t[16];
#pragma unroll
        for (int m = 0; m < 16; ++m) t[m] = Ls[kc + m][nr];
        unsigned short* op = Wt + (size_t)(nt + nr) * 1024 + kt + kc;
        *(int4*)op       = *(const int4*)&t[0];
        *(int4*)(op + 8) = *(const int4*)&t[8];
    }
}

// ---------------------------------------------------------------------------
// 128x128 tile bf16 GEMM (K=1024, BK=64), A [M][K] bf16, Bt [N][K] bf16.
// 4 waves 2x2, 64x64 per wave (4x4 16x16x32 frags). XOR-swizzled LDS (G4).
// MODE 0: qkv epilogue (bias + scatter bf16 to [which][b][h][l][dh]).
// MODE 1: out epilogue (bias + fp32 store [M][1024]).
// ---------------------------------------------------------------------------
template<int MODE>
__global__ __launch_bounds__(256)
void gemm128_kernel(const unsigned short* __restrict__ A,
                    const unsigned short* __restrict__ Bt,
                    const float* __restrict__ b0, const float* __restrict__ b1,
                    const float* __restrict__ b2,
                    void* __restrict__ outp)
{
    __shared__ __align__(16) unsigned short As[128][64];
    __shared__ __align__(16) unsigned short Bs[128][64];

    const int tid  = threadIdx.x;
    const int lane = tid & 63;
    const int w    = tid >> 6;
    const int wr   = w >> 1, wc = w & 1;
    const int l16  = lane & 15, lk = lane >> 4;

    const int m0 = blockIdx.y * 128;
    const int n0 = blockIdx.x * 128;

    const int r8  = tid >> 3;           // 0..31
    const int cb  = tid & 7;            // 16B block 0..7
    const int swz = cb ^ (r8 & 7);

    const unsigned short* Ap = A  + (size_t)m0 * 1024 + cb * 8;
    const unsigned short* Bp = Bt + (size_t)n0 * 1024 + cb * 8;

    f32x4 acc[4][4];
#pragma unroll
    for (int i = 0; i < 4; ++i)
#pragma unroll
        for (int j = 0; j < 4; ++j) acc[i][j] = f32x4{0.f, 0.f, 0.f, 0.f};

    for (int k0 = 0; k0 < 1024; k0 += 64) {
        __syncthreads();
#pragma unroll
        for (int c = 0; c < 4; ++c) {
            const int row = c * 32 + r8;          // row&7 == r8&7
            bf16x8 av = ld_frag(Ap + (size_t)row * 1024 + k0);
            bf16x8 bv = ld_frag(Bp + (size_t)row * 1024 + k0);
            *(bf16x8*)&As[row][swz * 8] = av;
            *(bf16x8*)&Bs[row][swz * 8] = bv;
        }
        __syncthreads();

#pragma unroll
        for (int kk = 0; kk < 2; ++kk) {
            bf16x8 af[4], bfr[4];
#pragma unroll
            for (int fm = 0; fm < 4; ++fm) {
                const int row = wr * 64 + fm * 16 + l16;
                const int kb  = kk * 4 + lk;
                af[fm] = ld_frag(&As[row][(kb ^ (row & 7)) * 8]);
            }
#pragma unroll
            for (int fn = 0; fn < 4; ++fn) {
                const int row = wc * 64 + fn * 16 + l16;
                const int kb  = kk * 4 + lk;
                bfr[fn] = ld_frag(&Bs[row][(kb ^ (row & 7)) * 8]);
            }
#pragma unroll
            for (int fm = 0; fm < 4; ++fm)
#pragma unroll
                for (int fn = 0; fn < 4; ++fn)
                    acc[fm][fn] = mfma_bf16(af[fm], bfr[fn], acc[fm][fn]);
        }
    }

    if (MODE == 0) {
        const int which = n0 >> 10;
        const float* bias = (which == 0) ? b0 : (which == 1) ? b1 : b2;
        unsigned short* out = (unsigned short*)outp
                            + (size_t)which * ((size_t)BB * HH * LL * DHH);
        const int c00 = n0 & 1023;
#pragma unroll
        for (int fm = 0; fm < 4; ++fm)
#pragma unroll
            for (int fn = 0; fn < 4; ++fn)
#pragma unroll
                for (int r = 0; r < 4; ++r) {
                    const int grow = m0 + wr * 64 + fm * 16 + lk * 4 + r;
                    const int c    = c00 + wc * 64 + fn * 16 + l16;
                    const float v  = acc[fm][fn][r] + bias[c];
                    const int b = grow >> 11, i = grow & 2047;
                    const int h = c >> 6,     d = c & 63;
                    out[(((size_t)(b * HH + h)) * LL + i) * DHH + d] = f2bf(v);
                }
    } else {
        float* out = (float*)outp;
#pragma unroll
        for (int fm = 0; fm < 4; ++fm)
#pragma unroll
            for (int fn = 0; fn < 4; ++fn)
#pragma unroll
                for (int r = 0; r < 4; ++r) {
                    const int grow = m0 + wr * 64 + fm * 16 + lk * 4 + r;
                    const int gcol = n0 + wc * 64 + fn * 16 + l16;
                    out[(size_t)grow * DD + gcol] = acc[fm][fn][r] + b0[gcol];
                }
    }
}

// ---------------------------------------------------------------------------
// V transpose: vws [bh][l][d] -> vT [bh][d][l]. 64x64 tiles, 256 threads.
// ---------------------------------------------------------------------------
__global__ __launch_bounds__(256)
void v_transpose_kernel(const unsigned short* __restrict__ vws,
                        unsigned short* __restrict__ vT)
{
    __shared__ unsigned short Ls[64][72];
    const int bh = blockIdx.y;
    const int i0 = blockIdx.x * 64;
    const int tid = threadIdx.x;

    {
        const int r = tid >> 2, c = (tid & 3) * 16;
        const unsigned short* vp = vws + ((size_t)bh * LL + i0 + r) * DHH + c;
        *(int4*)&Ls[r][c]     = *(const int4*)vp;
        *(int4*)&Ls[r][c + 8] = *(const int4*)(vp + 8);
    }
    __syncthreads();
    {
        const int d = tid >> 2, c = (tid & 3) * 16;
        unsigned short tmp[16];
#pragma unroll
        for (int m = 0; m < 16; ++m) tmp[m] = Ls[c + m][d];
        unsigned short* op = vT + ((size_t)bh * DHH + d) * LL + i0 + c;
        *(int4*)op       = *(const int4*)&tmp[0];
        *(int4*)(op + 8) = *(const int4*)&tmp[8];
    }
}

// ---------------------------------------------------------------------------
// Fused causal attention (unchanged from R7). QBLK=32, 128 threads (2 waves),
// zero barriers. Balanced grid. Max-free softmax. Coalesced NT attn store.
// ---------------------------------------------------------------------------
__global__ __launch_bounds__(128, 4)
void attn_kernel(const unsigned short* __restrict__ qws,
                 const unsigned short* __restrict__ kws,
                 const unsigned short* __restrict__ vT,
                 const float* __restrict__ B_graph,
                 const float* __restrict__ lattice,
                 const float* __restrict__ Wl,
                 const float* __restrict__ bl,
                 float* __restrict__ attn_out,
                 unsigned short* __restrict__ out_pre)
{
    const int n  = blockIdx.x;           // [0, 2048)
    const int bh = n & 31;
    const int tb = n >> 5;               // [0, 64)
    const int kg = tb >> 3, tt = tb & 7;
    const int ib = 8 * kg + ((kg & 1) ? 7 - tt : tt);
    const int b = bh >> 4, h = bh & 15;
    const int i0 = ib * 32;
    const int nj = (ib >> 1) + 1;

    __shared__ unsigned short Ps[2][16][72];

    const int tid  = threadIdx.x;
    const int lane = tid & 63;
    const int w    = tid >> 6;
    const int l16  = lane & 15, lk = lane >> 4;

    float lb = bl[h];
#pragma unroll
    for (int t = 0; t < 6; ++t) lb += lattice[b * 6 + t] * Wl[t * HH + h];

    const int bhh = b * HH + h;
    const unsigned short* qbase = qws + ((size_t)bhh * LL + i0) * DHH;
    const unsigned short* kbase = kws + (size_t)bhh * LL * DHH;
    const unsigned short* vtb   = vT + (size_t)bhh * DHH * LL;
    const float* gb = B_graph + (size_t)b * LL * LL;

    bf16x8 qa0 = ld_frag(qbase + (size_t)(w * 16 + l16) * DHH + lk * 8);
    bf16x8 qa1 = ld_frag(qbase + (size_t)(w * 16 + l16) * DHH + 32 + lk * 8);

    const int gi0 = i0 + w * 16 + lk * 4;

    float s_run[4];
#pragma unroll
    for (int r = 0; r < 4; ++r) s_run[r] = 0.f;

    auto loadK = [&](int jb, bf16x8* kb) {
        const unsigned short* kt = kbase + (size_t)jb * 64 * DHH;
#pragma unroll
        for (int fn = 0; fn < 4; ++fn) {
            kb[2 * fn]     = ld_frag(kt + (size_t)(fn * 16 + l16) * DHH + lk * 8);
            kb[2 * fn + 1] = ld_frag(kt + (size_t)(fn * 16 + l16) * DHH + 32 + lk * 8);
        }
    };

    auto accumTile = [&](int jb, const bf16x8* kb) {
#pragma unroll
        for (int fn = 0; fn < 4; ++fn) {
            f32x4 z = {0.f, 0.f, 0.f, 0.f};
            z = mfma_bf16(qa0, kb[2 * fn], z);
            z = mfma_bf16(qa1, kb[2 * fn + 1], z);
            const int gj = jb * 64 + fn * 16 + l16;
#pragma unroll
            for (int r = 0; r < 4; ++r) {
                const int gi = gi0 + r;
                const float sv = fmaf(z[r], 0.125f, lb + gb[(size_t)gi * LL + gj]);
                s_run[r] += (gj > gi) ? 0.f : __expf(sv);
            }
        }
    };

    // pass A: denominators
    {
        int jb = 0;
        for (; jb + 2 <= nj; jb += 2) {
            bf16x8 k0[8], k1[8];
            loadK(jb, k0);
            loadK(jb + 1, k1);
            accumTile(jb, k0);
            accumTile(jb + 1, k1);
        }
        if (jb < nj) {
            bf16x8 k0[8];
            loadK(jb, k0);
            accumTile(jb, k0);
        }
    }
#pragma unroll
    for (int off = 1; off < 16; off <<= 1)
#pragma unroll
        for (int r = 0; r < 4; ++r) s_run[r] += __shfl_xor(s_run[r], off, 64);

    float inv_s[4];
#pragma unroll
    for (int r = 0; r < 4; ++r) inv_s[r] = 1.0f / s_run[r];

    f32x4 oacc[4];
#pragma unroll
    for (int fn = 0; fn < 4; ++fn) oacc[fn] = f32x4{0.f, 0.f, 0.f, 0.f};

    // pass B: attn write + PV (no barriers)
    for (int jb = 0; jb < nj; ++jb) {
        bf16x8 kb[8];
        loadK(jb, kb);

#pragma unroll
        for (int fn = 0; fn < 4; ++fn) {
            f32x4 z = {0.f, 0.f, 0.f, 0.f};
            z = mfma_bf16(qa0, kb[2 * fn], z);
            z = mfma_bf16(qa1, kb[2 * fn + 1], z);
            const int gj = jb * 64 + fn * 16 + l16;
#pragma unroll
            for (int r = 0; r < 4; ++r) {
                const int gi = gi0 + r;
                const float sv = fmaf(z[r], 0.125f, lb + gb[(size_t)gi * LL + gj]);
                const float p = ((gj > gi) ? 0.f : __expf(sv)) * inv_s[r];
                Ps[w][lk * 4 + r][fn * 16 + l16] = f2bf(p);
            }
        }

        const int jc0 = jb * 64 + l16 * 4;
#pragma unroll
        for (int s = 0; s < 4; ++s) {
            const int row = s * 4 + lk;
            const int gi  = i0 + w * 16 + row;
            const unsigned short* pp = &Ps[w][row][l16 * 4];
            ushort4 pb = *(const ushort4*)pp;
            f32x4 pv;
            pv.x = bf2f(pb.x); pv.y = bf2f(pb.y);
            pv.z = bf2f(pb.z); pv.w = bf2f(pb.w);
            __builtin_nontemporal_store(
                pv, (f32x4*)&attn_out[((size_t)bhh * LL + gi) * LL + jc0]);
        }

        bf16x8 pa0 = ld_frag(&Ps[w][l16][lk * 8]);
        bf16x8 pa1 = ld_frag(&Ps[w][l16][32 + lk * 8]);
#pragma unroll
        for (int fn = 0; fn < 4; ++fn) {
            const unsigned short* vp = vtb + (size_t)(fn * 16 + l16) * LL + jb * 64;
            bf16x8 vb0 = ld_frag(vp + lk * 8);
            bf16x8 vb1 = ld_frag(vp + 32 + lk * 8);
            oacc[fn] = mfma_bf16(pa0, vb0, oacc[fn]);
            oacc[fn] = mfma_bf16(pa1, vb1, oacc[fn]);
        }
    }

    // zero-fill strictly-upper columns
    const int zc0 = nj * 64;
    if (zc0 < LL) {
        const int nz4 = (LL - zc0) >> 2;
        const f32x4 z4 = {0.f, 0.f, 0.f, 0.f};
        for (int row = 0; row < 32; ++row) {
            f32x4* zp = (f32x4*)(attn_out + ((size_t)bhh * LL + i0 + row) * LL + zc0);
            for (int c4 = tid; c4 < nz4; c4 += 128)
                __builtin_nontemporal_store(z4, &zp[c4]);
        }
    }

#pragma unroll
    for (int fn = 0; fn < 4; ++fn)
#pragma unroll
        for (int r = 0; r < 4; ++r) {
            const int gi = gi0 + r;
            const int d  = fn * 16 + l16;
            out_pre[((size_t)(b * LL + gi)) * NH + h * DHH + d] = f2bf(oacc[fn][r]);
        }
}

// ---------------------------------------------------------------------------
extern "C" void kernel_launch(void* const* d_in, const int* in_sizes, int n_in,
                              void* d_out, int out_size, void* d_ws, size_t ws_size,
                              hipStream_t stream)
{
    const float* x       = (const float*)d_in[0];
    const float* lattice = (const float*)d_in[1];
    const float* B_graph = (const float*)d_in[2];
    const float* Wq = (const float*)d_in[4];
    const float* bq = (const float*)d_in[5];
    const float* Wk = (const float*)d_in[6];
    const float* bk = (const float*)d_in[7];
    const float* Wv = (const float*)d_in[8];
    const float* bv = (const float*)d_in[9];
    const float* Wo = (const float*)d_in[10];
    const float* bo = (const float*)d_in[11];
    const float* Wl = (const float*)d_in[12];
    const float* bl = (const float*)d_in[13];

    float* out  = (float*)d_out;
    float* attn = out + (size_t)BB * LL * DD;

    const size_t PHL = (size_t)BB * HH * LL * DHH;   // 4.19M elems per tensor
    unsigned short* qkv    = (unsigned short*)d_ws;  // 3*PHL
    unsigned short* qw     = qkv;
    unsigned short* kw     = qkv + PHL;
    unsigned short* vw     = qkv + 2 * PHL;
    unsigned short* outpre = qkv + 3 * PHL;          // [B][L][NH] bf16 (attn out)
    unsigned short* Wqkvt  = outpre;                 // ALIAS: W^T lives here until attn runs
    unsigned short* xb     = outpre + (size_t)BB * LL * NH;  // x bf16 [4096][1024]
    unsigned short* vT     = xb;                     // ALIAS: vT overwrites xb after qkv GEMM
    unsigned short* Wot    = xb + (size_t)BB * LL * DD;      // Wo^T bf16 [1024][1024]

    // 1) converts
    conv_x_kernel<<<dim3((BB * LL * DD) / (256 * 8)), 256, 0, stream>>>(x, xb);
    conv_w_kernel<<<dim3(16, 16, 4), 256, 0, stream>>>(Wq, Wk, Wv, Wo, Wqkvt, Wot);

    // 2) fused QKV GEMM: [4096,1024] x [1024,3072]
    gemm128_kernel<0><<<dim3(3 * NH / 128, (BB * LL) / 128), 256, 0, stream>>>(
        xb, Wqkvt, bq, bk, bv, qkv);

    // 3) V transpose (overwrites xb region)
    v_transpose_kernel<<<dim3(LL / 64, BB * HH), 256, 0, stream>>>(vw, vT);

    // 4) attention
    attn_kernel<<<dim3(BB * HH * (LL / 32)), 128, 0, stream>>>(
        qw, kw, vT, B_graph, lattice, Wl, bl, attn, outpre);

    // 5) output projection: [4096,1024] x [1024,1024] -> fp32
    gemm128_kernel<1><<<dim3(DD / 128, (BB * LL) / 128), 256, 0, stream>>>(
        outpre, Wot, bo, bo, bo, out);
}